// Round 2
// baseline (324.285 us; speedup 1.0000x reference)
//
#include <hip/hip_runtime.h>
#include <stdint.h>

// Problem constants (from reference)
#define N_NODES 50000
#define DEG     32
#define IN_DIM  256
#define K1      512   // 2*IN_DIM
#define HID     256
#define OUT_DIM 128

#define MT   32    // nodes per block tile
#define CSTR 520   // combined LDS row stride in bf16 elems (512 + 8 pad; 1040B row = 16B-aligned)
#define HSTR 264   // h LDS row stride in bf16 elems (256 + 8 pad; 528B row = 16B-aligned)

typedef __bf16 bf16x8 __attribute__((ext_vector_type(8)));
typedef float  f32x4  __attribute__((ext_vector_type(4)));

__device__ __forceinline__ unsigned short f2bf(float f) {
    union { float f; unsigned u; } v; v.f = f;
    unsigned r = v.u + 0x7fffu + ((v.u >> 16) & 1u);  // RNE (inputs finite)
    return (unsigned short)(r >> 16);
}
__device__ __forceinline__ float bf2f(unsigned short h) {
    union { unsigned u; float f; } v; v.u = ((unsigned)h) << 16;
    return v.f;
}

// ---------------- fp32 -> bf16 conversion (elementwise) ----------------
__global__ __launch_bounds__(256)
void cvt_f32_bf16(const float* __restrict__ src,
                  unsigned short* __restrict__ dst, int n) {
    int i = (blockIdx.x * blockDim.x + threadIdx.x) * 4;
    if (i + 3 < n) {
        float4 f = *(const float4*)(src + i);
        ushort4 o;
        o.x = f2bf(f.x); o.y = f2bf(f.y); o.z = f2bf(f.z); o.w = f2bf(f.w);
        *(ushort4*)(dst + i) = o;
    } else {
        for (; i < n; ++i) dst[i] = f2bf(src[i]);
    }
}

// ---------------- fused gather-mean + GEMM1 + GEMM2 (bf16 MFMA) ----------------
// MFMA fragment layouts (measured, learn_hip m89/m91/m120):
//   A operand: lane holds A[m = lane&15][k = (lane>>4)*8 + j], j=0..7
//   B operand (W row-major [n][k]): lane holds W[n = lane&15][k = (lane>>4)*8 + j]
//   C/D: col(n) = lane&15, row(m) = (lane>>4)*4 + reg
__global__ __launch_bounds__(256)
void sage_fused(const unsigned short* __restrict__ featb,  // [N, 256] bf16
                const int*            __restrict__ nbr,    // [N, 32]
                const unsigned short* __restrict__ W1b,    // [256, 512] bf16
                const float*          __restrict__ b1,     // [256]
                const unsigned short* __restrict__ W2b,    // [128, 256] bf16
                const float*          __restrict__ b2,     // [128]
                float*                __restrict__ out)    // [N, 128]
{
    __shared__ __align__(16) unsigned short sC[MT * CSTR]; // 33280 B
    __shared__ __align__(16) unsigned short sH[MT * HSTR]; // 16896 B
    __shared__ int sNbr[MT * DEG];                         //  4096 B  (total 54272 B)

    const int tid  = threadIdx.x;
    const int lane = tid & 63;
    const int wave = tid >> 6;
    const int base = blockIdx.x * MT;

    // ---- Phase 0: stage neighbor indices into LDS (guarded + clamped) ----
    {
        const int g0  = base * DEG;
        const int lim = N_NODES * DEG;
        #pragma unroll
        for (int j = 0; j < 4; ++j) {
            int li = tid * 4 + j;          // 0..1023
            int gi = g0 + li;
            int v = 0;
            if (gi < lim) v = nbr[gi];
            v = v < 0 ? 0 : (v >= N_NODES ? N_NODES - 1 : v);  // fault-proof
            sNbr[li] = v;
        }
    }
    __syncthreads();

    // ---- Phase 1: gather + mean + concat -> sC (bf16) ----
    // wave handles 8 nodes; lane covers 4 contiguous feature elems (256 = 64*4)
    for (int i = wave * 8; i < wave * 8 + 8; ++i) {
        const int node = base + i;
        unsigned short* crow = &sC[i * CSTR];
        if (node < N_NODES) {
            ushort4 selfv = *(const ushort4*)(featb + (size_t)node * IN_DIM + lane * 4);
            *(ushort4*)(crow + lane * 4) = selfv;
            const int* nrow = &sNbr[i * DEG];
            float ax = 0.f, ay = 0.f, az = 0.f, aw = 0.f;
            #pragma unroll 4
            for (int d = 0; d < DEG; ++d) {
                int nb = nrow[d];  // LDS broadcast read (same addr across wave)
                ushort4 v = *(const ushort4*)(featb + (size_t)nb * IN_DIM + lane * 4);
                ax += bf2f(v.x); ay += bf2f(v.y); az += bf2f(v.z); aw += bf2f(v.w);
            }
            const float s = 1.0f / 32.0f;
            ushort4 mv;
            mv.x = f2bf(ax * s); mv.y = f2bf(ay * s);
            mv.z = f2bf(az * s); mv.w = f2bf(aw * s);
            *(ushort4*)(crow + IN_DIM + lane * 4) = mv;
        } else {
            ushort4 z; z.x = z.y = z.z = z.w = 0;
            *(ushort4*)(crow + lane * 4) = z;
            *(ushort4*)(crow + IN_DIM + lane * 4) = z;
        }
    }
    __syncthreads();

    const int r = lane & 15;      // fragment row / output col
    const int q = lane >> 4;      // quad

    // ---- Phase 2: h = relu(combined @ W1^T + b1), wave computes cols [wave*64, wave*64+64) ----
    {
        f32x4 acc[2][4];
        #pragma unroll
        for (int mt = 0; mt < 2; ++mt)
            #pragma unroll
            for (int nt = 0; nt < 4; ++nt)
                acc[mt][nt] = (f32x4){0.f, 0.f, 0.f, 0.f};

        for (int k0 = 0; k0 < K1; k0 += 32) {
            bf16x8 a0 = *(const bf16x8*)(&sC[r * CSTR + k0 + q * 8]);
            bf16x8 a1 = *(const bf16x8*)(&sC[(16 + r) * CSTR + k0 + q * 8]);
            #pragma unroll
            for (int nt = 0; nt < 4; ++nt) {
                int n = wave * 64 + nt * 16 + r;
                bf16x8 b = *(const bf16x8*)(W1b + (size_t)n * K1 + k0 + q * 8);
                acc[0][nt] = __builtin_amdgcn_mfma_f32_16x16x32_bf16(a0, b, acc[0][nt], 0, 0, 0);
                acc[1][nt] = __builtin_amdgcn_mfma_f32_16x16x32_bf16(a1, b, acc[1][nt], 0, 0, 0);
            }
        }
        #pragma unroll
        for (int nt = 0; nt < 4; ++nt) {
            int n = wave * 64 + nt * 16 + r;
            float bias = b1[n];
            #pragma unroll
            for (int mt = 0; mt < 2; ++mt)
                #pragma unroll
                for (int g = 0; g < 4; ++g) {
                    int m = mt * 16 + q * 4 + g;
                    float v = acc[mt][nt][g] + bias;
                    sH[m * HSTR + n] = f2bf(v > 0.f ? v : 0.f);
                }
        }
    }
    __syncthreads();

    // ---- Phase 3: out = relu(h @ W2^T + b2), wave computes cols [wave*32, wave*32+32) ----
    {
        f32x4 acc[2][2];
        #pragma unroll
        for (int mt = 0; mt < 2; ++mt)
            #pragma unroll
            for (int nt = 0; nt < 2; ++nt)
                acc[mt][nt] = (f32x4){0.f, 0.f, 0.f, 0.f};

        for (int k0 = 0; k0 < HID; k0 += 32) {
            bf16x8 a0 = *(const bf16x8*)(&sH[r * HSTR + k0 + q * 8]);
            bf16x8 a1 = *(const bf16x8*)(&sH[(16 + r) * HSTR + k0 + q * 8]);
            #pragma unroll
            for (int nt = 0; nt < 2; ++nt) {
                int o = wave * 32 + nt * 16 + r;
                bf16x8 b = *(const bf16x8*)(W2b + (size_t)o * HID + k0 + q * 8);
                acc[0][nt] = __builtin_amdgcn_mfma_f32_16x16x32_bf16(a0, b, acc[0][nt], 0, 0, 0);
                acc[1][nt] = __builtin_amdgcn_mfma_f32_16x16x32_bf16(a1, b, acc[1][nt], 0, 0, 0);
            }
        }
        #pragma unroll
        for (int nt = 0; nt < 2; ++nt) {
            int o = wave * 32 + nt * 16 + r;
            float bias = b2[o];
            #pragma unroll
            for (int mt = 0; mt < 2; ++mt)
                #pragma unroll
                for (int g = 0; g < 4; ++g) {
                    int m = mt * 16 + q * 4 + g;
                    int node = base + m;
                    if (node < N_NODES) {
                        float v = acc[mt][nt][g] + bias;
                        out[(size_t)node * OUT_DIM + o] = v > 0.f ? v : 0.f;
                    }
                }
        }
    }
}

// ---------------- naive fp32 fallback (only if ws too small for bf16 staging) ----------------
__global__ __launch_bounds__(256)
void sage_naive(const float* __restrict__ feat, const int* __restrict__ nbr,
                const float* __restrict__ W1, const float* __restrict__ b1,
                const float* __restrict__ W2, const float* __restrict__ b2,
                float* __restrict__ out) {
    __shared__ float comb[K1];
    __shared__ float h[HID];
    const int node = blockIdx.x;
    const int t = threadIdx.x;  // 256
    comb[t] = feat[(size_t)node * IN_DIM + t];
    float acc = 0.f;
    for (int d = 0; d < DEG; ++d) {
        int nb = nbr[node * DEG + d];
        nb = nb < 0 ? 0 : (nb >= N_NODES ? N_NODES - 1 : nb);
        acc += feat[(size_t)nb * IN_DIM + t];
    }
    comb[IN_DIM + t] = acc * (1.0f / 32.0f);
    __syncthreads();
    float s = b1[t];
    for (int k = 0; k < K1; ++k) s += comb[k] * W1[(size_t)t * K1 + k];
    h[t] = s > 0.f ? s : 0.f;
    __syncthreads();
    if (t < OUT_DIM) {
        float s2 = b2[t];
        for (int k = 0; k < HID; ++k) s2 += h[k] * W2[(size_t)t * HID + k];
        out[(size_t)node * OUT_DIM + t] = s2 > 0.f ? s2 : 0.f;
    }
}

extern "C" void kernel_launch(void* const* d_in, const int* in_sizes, int n_in,
                              void* d_out, int out_size, void* d_ws, size_t ws_size,
                              hipStream_t stream) {
    const float* feat = (const float*)d_in[0];
    const int*   nbr  = (const int*)d_in[1];
    const float* W1   = (const float*)d_in[2];
    const float* b1   = (const float*)d_in[3];
    const float* W2   = (const float*)d_in[4];
    const float* b2   = (const float*)d_in[5];
    float* out = (float*)d_out;

    const size_t feat_elems = (size_t)N_NODES * IN_DIM;   // 12.8M
    const size_t w1_elems   = (size_t)HID * K1;           // 131072
    const size_t w2_elems   = (size_t)OUT_DIM * HID;      // 32768
    const size_t need = (feat_elems + w1_elems + w2_elems) * sizeof(unsigned short);

    if (ws_size >= need) {
        unsigned short* featb = (unsigned short*)d_ws;
        unsigned short* W1b   = featb + feat_elems;
        unsigned short* W2b   = W1b + w1_elems;

        cvt_f32_bf16<<<(int)((feat_elems / 4 + 255) / 256), 256, 0, stream>>>(feat, featb, (int)feat_elems);
        cvt_f32_bf16<<<(int)((w1_elems   / 4 + 255) / 256), 256, 0, stream>>>(W1, W1b, (int)w1_elems);
        cvt_f32_bf16<<<(int)((w2_elems   / 4 + 255) / 256), 256, 0, stream>>>(W2, W2b, (int)w2_elems);

        sage_fused<<<(N_NODES + MT - 1) / MT, 256, 0, stream>>>(featb, nbr, W1b, b1, W2b, b2, out);
    } else {
        sage_naive<<<N_NODES, 256, 0, stream>>>(feat, nbr, W1, b1, W2, b2, out);
    }
}

// Round 3
// 281.449 us; speedup vs baseline: 1.1522x; 1.1522x over previous
//
#include <hip/hip_runtime.h>
#include <stdint.h>

// Problem constants (from reference)
#define N_NODES 50000
#define DEG     32
#define IN_DIM  256
#define K1      512   // 2*IN_DIM
#define HID     256
#define OUT_DIM 128

#define MT   32    // nodes per block tile (GEMM kernel)
#define CSTR 520   // combined LDS row stride in bf16 elems (1040 B = 65*16, keeps 16B alignment)
#define HSTR 264   // h LDS row stride in bf16 elems (528 B = 33*16)

typedef __bf16 bf16x8 __attribute__((ext_vector_type(8)));
typedef float  f32x4  __attribute__((ext_vector_type(4)));

__device__ __forceinline__ unsigned short f2bf(float f) {
    union { float f; unsigned u; } v; v.f = f;
    unsigned r = v.u + 0x7fffu + ((v.u >> 16) & 1u);  // RNE (inputs finite)
    return (unsigned short)(r >> 16);
}
__device__ __forceinline__ float bf2f(unsigned short h) {
    union { unsigned u; float f; } v; v.u = ((unsigned)h) << 16;
    return v.f;
}
__device__ __forceinline__ int clampN(int v) {
    return v < 0 ? 0 : (v >= N_NODES ? N_NODES - 1 : v);
}

// ---------------- fp32 -> bf16 conversion (elementwise) ----------------
__global__ __launch_bounds__(256)
void cvt_f32_bf16(const float* __restrict__ src,
                  unsigned short* __restrict__ dst, int n) {
    int i = (blockIdx.x * blockDim.x + threadIdx.x) * 4;
    if (i + 3 < n) {
        float4 f = *(const float4*)(src + i);
        ushort4 o;
        o.x = f2bf(f.x); o.y = f2bf(f.y); o.z = f2bf(f.z); o.w = f2bf(f.w);
        *(ushort4*)(dst + i) = o;
    } else {
        for (; i < n; ++i) dst[i] = f2bf(src[i]);
    }
}

// ---------------- gather + mean kernel: max memory-level parallelism ----------------
// One block (4 waves) per node. Wave w sums neighbors 8w..8w+7 with all 8
// 512B row-loads issued back-to-back (full unroll), then LDS tree-reduce.
// Tiny LDS/VGPR footprint -> 8 blocks/CU (32 waves) -> ~131 KB loads in
// flight per CU, far above the ~54 KB BW-latency product: BW-bound.
__global__ __launch_bounds__(256)
void gather_mean(const unsigned short* __restrict__ featb,  // [N, 256] bf16
                 const int*            __restrict__ nbr,    // [N, 32]
                 unsigned short*       __restrict__ meanb)  // [N, 256] bf16 out
{
    __shared__ int   sIdx[DEG];
    __shared__ float sRed[4][IN_DIM];  // 4 KB

    const int n    = blockIdx.x;
    const int tid  = threadIdx.x;
    const int lane = tid & 63;
    const int wave = tid >> 6;

    if (tid < DEG) sIdx[tid] = clampN(nbr[n * DEG + tid]);
    __syncthreads();

    // 8 fully-independent row loads (8B/lane each)
    ushort4 v[8];
    #pragma unroll
    for (int j = 0; j < 8; ++j) {
        int nb = sIdx[wave * 8 + j];
        v[j] = *(const ushort4*)(featb + (size_t)nb * IN_DIM + lane * 4);
    }
    float a0 = 0.f, a1 = 0.f, a2 = 0.f, a3 = 0.f;
    #pragma unroll
    for (int j = 0; j < 8; ++j) {
        a0 += bf2f(v[j].x); a1 += bf2f(v[j].y);
        a2 += bf2f(v[j].z); a3 += bf2f(v[j].w);
    }
    *(float4*)&sRed[wave][lane * 4] = (float4){a0, a1, a2, a3};
    __syncthreads();

    float s = sRed[0][tid] + sRed[1][tid] + sRed[2][tid] + sRed[3][tid];
    meanb[(size_t)n * IN_DIM + tid] = f2bf(s * (1.0f / 32.0f));
}

// ---------------- fused GEMM1 + GEMM2 (bf16 MFMA) ----------------
// MFMA fragment layouts (measured, learn_hip m89/m91/m120):
//   A operand: lane holds A[m = lane&15][k = (lane>>4)*8 + j], j=0..7
//   B operand (W row-major [n][k]): lane holds W[n = lane&15][k = (lane>>4)*8 + j]
//   C/D: col(n) = lane&15, row(m) = (lane>>4)*4 + reg
__global__ __launch_bounds__(256)
void sage_gemm(const unsigned short* __restrict__ featb,  // [N, 256] bf16
               const unsigned short* __restrict__ meanb,  // [N, 256] bf16
               const unsigned short* __restrict__ W1b,    // [256, 512] bf16
               const float*          __restrict__ b1,     // [256]
               const unsigned short* __restrict__ W2b,    // [128, 256] bf16
               const float*          __restrict__ b2,     // [128]
               float*                __restrict__ out)    // [N, 128]
{
    __shared__ __align__(16) unsigned short sC[MT * CSTR]; // 33280 B
    __shared__ __align__(16) unsigned short sH[MT * HSTR]; // 16896 B  (50176 B total -> 3 blocks/CU)

    const int tid  = threadIdx.x;
    const int lane = tid & 63;
    const int wave = tid >> 6;
    const int base = blockIdx.x * MT;

    // ---- Phase 1: stage combined = [self | mean] rows into sC ----
    // lanes 0-31 cover the 512B self row, lanes 32-63 the 512B mean row;
    // LDS offset lane*8 elems lands mean exactly at elem 256. 16B/lane.
    for (int i = wave * 8; i < wave * 8 + 8; ++i) {
        const int node = base + i;
        if (node < N_NODES) {
            const unsigned short* src = (lane < 32)
                ? featb + (size_t)node * IN_DIM + lane * 8
                : meanb + (size_t)node * IN_DIM + (lane - 32) * 8;
            bf16x8 val = *(const bf16x8*)src;
            *(bf16x8*)(&sC[i * CSTR + lane * 8]) = val;
        } else {
            bf16x8 z = (bf16x8){0, 0, 0, 0, 0, 0, 0, 0};
            *(bf16x8*)(&sC[i * CSTR + lane * 8]) = z;
        }
    }
    __syncthreads();

    const int r = lane & 15;      // fragment row / output col
    const int q = lane >> 4;      // quad

    // ---- Phase 2: h = relu(combined @ W1^T + b1), wave computes cols [wave*64, wave*64+64) ----
    {
        f32x4 acc[2][4];
        #pragma unroll
        for (int mt = 0; mt < 2; ++mt)
            #pragma unroll
            for (int nt = 0; nt < 4; ++nt)
                acc[mt][nt] = (f32x4){0.f, 0.f, 0.f, 0.f};

        for (int k0 = 0; k0 < K1; k0 += 32) {
            bf16x8 a0 = *(const bf16x8*)(&sC[r * CSTR + k0 + q * 8]);
            bf16x8 a1 = *(const bf16x8*)(&sC[(16 + r) * CSTR + k0 + q * 8]);
            #pragma unroll
            for (int nt = 0; nt < 4; ++nt) {
                int n = wave * 64 + nt * 16 + r;
                bf16x8 b = *(const bf16x8*)(W1b + (size_t)n * K1 + k0 + q * 8);
                acc[0][nt] = __builtin_amdgcn_mfma_f32_16x16x32_bf16(a0, b, acc[0][nt], 0, 0, 0);
                acc[1][nt] = __builtin_amdgcn_mfma_f32_16x16x32_bf16(a1, b, acc[1][nt], 0, 0, 0);
            }
        }
        #pragma unroll
        for (int nt = 0; nt < 4; ++nt) {
            int n = wave * 64 + nt * 16 + r;
            float bias = b1[n];
            #pragma unroll
            for (int mt = 0; mt < 2; ++mt)
                #pragma unroll
                for (int g = 0; g < 4; ++g) {
                    int m = mt * 16 + q * 4 + g;
                    float v = acc[mt][nt][g] + bias;
                    sH[m * HSTR + n] = f2bf(v > 0.f ? v : 0.f);
                }
        }
    }
    __syncthreads();

    // ---- Phase 3: out = relu(h @ W2^T + b2), wave computes cols [wave*32, wave*32+32) ----
    {
        f32x4 acc[2][2];
        #pragma unroll
        for (int mt = 0; mt < 2; ++mt)
            #pragma unroll
            for (int nt = 0; nt < 2; ++nt)
                acc[mt][nt] = (f32x4){0.f, 0.f, 0.f, 0.f};

        for (int k0 = 0; k0 < HID; k0 += 32) {
            bf16x8 a0 = *(const bf16x8*)(&sH[r * HSTR + k0 + q * 8]);
            bf16x8 a1 = *(const bf16x8*)(&sH[(16 + r) * HSTR + k0 + q * 8]);
            #pragma unroll
            for (int nt = 0; nt < 2; ++nt) {
                int o = wave * 32 + nt * 16 + r;
                bf16x8 b = *(const bf16x8*)(W2b + (size_t)o * HID + k0 + q * 8);
                acc[0][nt] = __builtin_amdgcn_mfma_f32_16x16x32_bf16(a0, b, acc[0][nt], 0, 0, 0);
                acc[1][nt] = __builtin_amdgcn_mfma_f32_16x16x32_bf16(a1, b, acc[1][nt], 0, 0, 0);
            }
        }
        #pragma unroll
        for (int nt = 0; nt < 2; ++nt) {
            int o = wave * 32 + nt * 16 + r;
            float bias = b2[o];
            #pragma unroll
            for (int mt = 0; mt < 2; ++mt)
                #pragma unroll
                for (int g = 0; g < 4; ++g) {
                    int m = mt * 16 + q * 4 + g;
                    int node = base + m;
                    if (node < N_NODES) {
                        float v = acc[mt][nt][g] + bias;
                        out[(size_t)node * OUT_DIM + o] = v > 0.f ? v : 0.f;
                    }
                }
        }
    }
}

// ---------------- naive fp32 fallback (only if ws too small) ----------------
__global__ __launch_bounds__(256)
void sage_naive(const float* __restrict__ feat, const int* __restrict__ nbr,
                const float* __restrict__ W1, const float* __restrict__ b1,
                const float* __restrict__ W2, const float* __restrict__ b2,
                float* __restrict__ out) {
    __shared__ float comb[K1];
    __shared__ float h[HID];
    const int node = blockIdx.x;
    const int t = threadIdx.x;  // 256
    comb[t] = feat[(size_t)node * IN_DIM + t];
    float acc = 0.f;
    for (int d = 0; d < DEG; ++d) {
        int nb = clampN(nbr[node * DEG + d]);
        acc += feat[(size_t)nb * IN_DIM + t];
    }
    comb[IN_DIM + t] = acc * (1.0f / 32.0f);
    __syncthreads();
    float s = b1[t];
    for (int k = 0; k < K1; ++k) s += comb[k] * W1[(size_t)t * K1 + k];
    h[t] = s > 0.f ? s : 0.f;
    __syncthreads();
    if (t < OUT_DIM) {
        float s2 = b2[t];
        for (int k = 0; k < HID; ++k) s2 += h[k] * W2[(size_t)t * HID + k];
        out[(size_t)node * OUT_DIM + t] = s2 > 0.f ? s2 : 0.f;
    }
}

extern "C" void kernel_launch(void* const* d_in, const int* in_sizes, int n_in,
                              void* d_out, int out_size, void* d_ws, size_t ws_size,
                              hipStream_t stream) {
    const float* feat = (const float*)d_in[0];
    const int*   nbr  = (const int*)d_in[1];
    const float* W1   = (const float*)d_in[2];
    const float* b1   = (const float*)d_in[3];
    const float* W2   = (const float*)d_in[4];
    const float* b2   = (const float*)d_in[5];
    float* out = (float*)d_out;

    const size_t feat_elems = (size_t)N_NODES * IN_DIM;   // 12.8M
    const size_t w1_elems   = (size_t)HID * K1;           // 131072
    const size_t w2_elems   = (size_t)OUT_DIM * HID;      // 32768
    const size_t mean_elems = (size_t)N_NODES * IN_DIM;   // 12.8M
    const size_t need = (feat_elems + w1_elems + w2_elems + mean_elems) * sizeof(unsigned short);

    if (ws_size >= need) {
        unsigned short* featb = (unsigned short*)d_ws;
        unsigned short* W1b   = featb + feat_elems;
        unsigned short* W2b   = W1b + w1_elems;
        unsigned short* meanb = W2b + w2_elems;

        cvt_f32_bf16<<<(int)((feat_elems / 4 + 255) / 256), 256, 0, stream>>>(feat, featb, (int)feat_elems);
        cvt_f32_bf16<<<(int)((w1_elems   / 4 + 255) / 256), 256, 0, stream>>>(W1, W1b, (int)w1_elems);
        cvt_f32_bf16<<<(int)((w2_elems   / 4 + 255) / 256), 256, 0, stream>>>(W2, W2b, (int)w2_elems);

        gather_mean<<<N_NODES, 256, 0, stream>>>(featb, nbr, meanb);
        sage_gemm<<<(N_NODES + MT - 1) / MT, 256, 0, stream>>>(featb, meanb, W1b, b1, W2b, b2, out);
    } else {
        sage_naive<<<N_NODES, 256, 0, stream>>>(feat, nbr, W1, b1, W2, b2, out);
    }
}